// Round 6
// baseline (604.250 us; speedup 1.0000x reference)
//
#include <hip/hip_runtime.h>
#include <hip/hip_bf16.h>

// T=16, N=4, Cin=hidden=64, C4=256, H=W=64
typedef float        f32x4  __attribute__((ext_vector_type(4)));
typedef unsigned int u32x4  __attribute__((ext_vector_type(4)));
typedef __bf16       bf16x8 __attribute__((ext_vector_type(8)));

__device__ __forceinline__ unsigned short f2bf(float f) {
    unsigned u = __builtin_bit_cast(unsigned, f);
    u += 0x7fffu + ((u >> 16) & 1u);          // RTN-even (finite inputs)
    return (unsigned short)(u >> 16);
}
__device__ __forceinline__ float bf2f(unsigned short u) {
    union { unsigned ui; float f; } c; c.ui = ((unsigned)u) << 16; return c.f;
}

// ---------------------------------------------------------------------------
// xT: [img][pix][ci] bf16  <-  x [img][ci][pix] f32
// ---------------------------------------------------------------------------
__global__ __launch_bounds__(256) void k_xT(const float* __restrict__ x,
                                            unsigned short* __restrict__ xT) {
    int bid = blockIdx.x;                // 1024
    int img = bid >> 4;
    int p   = (bid & 15) * 256 + threadIdx.x;
    const float* xi = x + (size_t)img * 64 * 4096 + p;
    unsigned short r[64];
#pragma unroll
    for (int ci = 0; ci < 64; ++ci) r[ci] = f2bf(xi[(size_t)ci * 4096]);
    u32x4* dst = (u32x4*)(xT + ((size_t)img * 4096 + p) * 64);
#pragma unroll
    for (int c8 = 0; c8 < 8; ++c8) dst[c8] = *(u32x4*)&r[c8 * 8];
}

// ---------------------------------------------------------------------------
// Pack weights [256][64][3][3] f32 -> A bf16 [row][ks][ci32] (canonical order)
// ks = half*9 + tap;  ci = half*32 + ci32.
// gatePerm: row = hc*4+g  ->  orig co = g*64+hc   (for Wh)
// ---------------------------------------------------------------------------
__global__ __launch_bounds__(256) void k_pack(const float* __restrict__ W,
                                              unsigned short* __restrict__ Ap,
                                              int gatePerm) {
    int idx = blockIdx.x * 256 + threadIdx.x;      // 576 blocks
    if (idx >= 256 * 576) return;
    int row = idx / 576, k = idx % 576;
    int ks = k / 32, c32 = k % 32;
    int half = ks / 9, tap = ks % 9;
    int ci = half * 32 + c32;
    int co = gatePerm ? ((row & 3) * 64 + (row >> 2)) : row;
    Ap[idx] = f2bf(W[((size_t)co * 64 + ci) * 9 + tap]);
}

// ---------------------------------------------------------------------------
// Unified MFMA conv core, A-operands direct from global (L2-resident).
// Barrier-free K-loop: per ks, 4 global A-loads + N_ LDS B-reads + 4*N_ MFMA.
// MODE0 (x2h): 16x16 tile, grid 64img*16tile*4cog = 4096, halo 18x18x64ci.
// MODE1 (step): 8x16 tile, grid 4img*32tile*4hcg  =  512, halo 10x18x64ci.
// ---------------------------------------------------------------------------
template<int MODE>
__global__ __launch_bounds__(256) void k_conv(
    const unsigned short* __restrict__ src,   // [img][4096][64] bf16
    const unsigned short* __restrict__ Ap,    // packed weights [row][18][32]
    unsigned short* __restrict__ ybf,         // MODE0: out, MODE1: in
    const float* __restrict__ ss,             // [2][256] scale/shift (MODE1)
    float* __restrict__ cst,                  // [4][64][4096] (MODE1)
    unsigned short* __restrict__ hout,        // [4][4096][64] (MODE1)
    float* __restrict__ out,                  // [16][4][64][4096] (MODE1)
    float2* __restrict__ prt,                 // [256ch][1024] BN partials (MODE0)
    int t, int first)
{
    constexpr int TH    = MODE ? 8 : 16;      // tile rows
    constexpr int N_    = MODE ? 2 : 4;       // pixel-row groups per wave
    constexpr int HR    = TH + 2;             // halo rows
    constexpr int TMSK  = MODE ? 31 : 15;
    constexpr int IMGSH = MODE ? 7 : 6;

    __shared__ __align__(16) unsigned short halo[HR * 18 * 64]; // 41472/23040 B

    const int bid  = blockIdx.x;
    const int grp  = bid & 3;                 // cog / hcg
    const int tile = (bid >> 2) & TMSK;
    const int img  = bid >> IMGSH;
    const int py0 = (tile >> 2) * TH, px0 = (tile & 3) * 16;
    const int tid = threadIdx.x;
    const int wv = tid >> 6, lane = tid & 63;
    const int cl = lane & 15, q = lane >> 4;
    const int rowbase = grp * 64;

    f32x4 acc[4][N_];
#pragma unroll
    for (int m = 0; m < 4; ++m)
#pragma unroll
        for (int n = 0; n < N_; ++n)
            acc[m][n] = (f32x4){0.f, 0.f, 0.f, 0.f};

    const bool skip = (MODE == 1) && first;

    if (!skip) {
        // ---- halo staging: HRx18 positions x 8 ci-slots, XOR-swizzled ----
        const unsigned short* sb = src + (size_t)img * 4096 * 64;
        char* hB = (char*)halo;
        for (int tau = tid; tau < HR * 144; tau += 256) {
            int s = tau & 7, hcc = (tau >> 3) % 18, hrr = tau / 144;
            int gy = py0 + hrr - 1, gx = px0 + hcc - 1;
            u32x4 v = {0u, 0u, 0u, 0u};
            if ((unsigned)gy < 64u && (unsigned)gx < 64u)
                v = *(const u32x4*)(sb + ((gy * 64 + gx) * 64 + s * 8));
            *(u32x4*)(hB + (hrr * 18 + hcc) * 128 + ((s * 16) ^ ((hcc & 7) << 4))) = v;
        }
        __syncthreads();

        // ---- per-lane A base: row = rowbase + m*16 + cl, 16B at q*16 ----
        const char* Apb = (const char*)Ap + (size_t)(rowbase + cl) * 1152 + q * 16;

        u32x4 af[4], afn[4];
#pragma unroll
        for (int m = 0; m < 4; ++m)
            af[m] = *(const u32x4*)(Apb + m * 18432);          // ks = 0

        for (int ks = 0; ks < 18; ++ks) {
            if (ks < 17) {
#pragma unroll
                for (int m = 0; m < 4; ++m)
                    afn[m] = *(const u32x4*)(Apb + m * 18432 + (ks + 1) * 64);
            }
            int tap = ks % 9, kb = ks / 9;
            int ky = tap / 3, kx = tap - ky * 3;
            int hcv  = cl + kx;
            int cbase = hcv * 128 + ((kb * 64 + q * 16) ^ ((hcv & 7) << 4));
#pragma unroll
            for (int n = 0; n < N_; ++n) {
                int hr = wv * N_ + n + ky;
                u32x4 bv = *(const u32x4*)(hB + hr * 2304 + cbase);
                bf16x8 bfr = __builtin_bit_cast(bf16x8, bv);
#pragma unroll
                for (int m = 0; m < 4; ++m)
                    acc[m][n] = __builtin_amdgcn_mfma_f32_16x16x32_bf16(
                        __builtin_bit_cast(bf16x8, af[m]), bfr, acc[m][n], 0, 0, 0);
            }
#pragma unroll
            for (int m = 0; m < 4; ++m) af[m] = afn[m];
        }
    }

    if (MODE == 0) {
        // ---- y = conv (bias cancels in train-mode BN; never added) ----
#pragma unroll
        for (int m = 0; m < 4; ++m) {
            int co = rowbase + m * 16 + q * 4;
#pragma unroll
            for (int n = 0; n < N_; ++n) {
                int pix = (py0 + wv * N_ + n) * 64 + px0 + cl;
                unsigned short* yp = ybf + (size_t)img * 256 * 4096 + pix;
#pragma unroll
                for (int j = 0; j < 4; ++j)
                    yp[(size_t)(co + j) * 4096] = f2bf(acc[m][n][j]);
            }
        }
        // ---- fused BN partial stats: per-block 64-channel (sum, sumsq) ----
        __syncthreads();                     // all waves done with halo reads
        float* bnred = (float*)halo;         // 512 B reuse
#pragma unroll
        for (int m = 0; m < 4; ++m) {
#pragma unroll
            for (int j = 0; j < 4; ++j) {
                float s = 0.f, qq = 0.f;
#pragma unroll
                for (int n = 0; n < N_; ++n) {
                    float v = acc[m][n][j];
                    s += v; qq += v * v;
                }
#pragma unroll
                for (int mask = 1; mask <= 8; mask <<= 1) {
                    s  += __shfl_xor(s,  mask, 64);
                    qq += __shfl_xor(qq, mask, 64);
                }
                if (cl == 0) {
                    int ci_ = (wv * 4 + q) * 16 + m * 4 + j;
                    bnred[ci_ * 2]     = s;
                    bnred[ci_ * 2 + 1] = qq;
                }
            }
        }
        __syncthreads();
        if (tid < 64) {
            int m_ = tid >> 4, qj = tid & 15;      // local ch = m*16 + q*4 + j
            float s = 0.f, qq = 0.f;
#pragma unroll
            for (int w = 0; w < 4; ++w) {
                int idx = ((w * 4 + (qj >> 2)) * 16 + m_ * 4 + (qj & 3)) * 2;
                s += bnred[idx]; qq += bnred[idx + 1];
            }
            prt[(size_t)(rowbase + tid) * 1024 + img * 16 + tile] = make_float2(s, qq);
        }
    } else {
        unsigned short* hbounce = halo;          // 4 KB reuse
        __syncthreads();                         // halo reads done (all waves)
#pragma unroll
        for (int m = 0; m < 4; ++m) {
            int hc = grp * 16 + m * 4 + q;
            float sc[4], sh[4];
#pragma unroll
            for (int j = 0; j < 4; ++j) {
                sc[j] = ss[j * 64 + hc];
                sh[j] = ss[256 + j * 64 + hc];
            }
#pragma unroll
            for (int n = 0; n < N_; ++n) {
                int pix = (py0 + wv * N_ + n) * 64 + px0 + cl;
                float tmp[4];
#pragma unroll
                for (int j = 0; j < 4; ++j) {
                    float yv = bf2f(ybf[((size_t)((t * 4 + img) * 256 + j * 64 + hc)) * 4096 + pix]);
                    tmp[j] = acc[m][n][j] + sc[j] * yv + sh[j];
                }
                float iv = 1.f / (1.f + __expf(-tmp[0]));
                float fv = 1.f / (1.f + __expf(-tmp[1]));
                float ov = 1.f / (1.f + __expf(-tmp[2]));
                float e2 = __expf(2.f * tmp[3]);
                float gv = 1.f - 2.f / (e2 + 1.f);
                size_t cidx = ((size_t)img * 64 + hc) * 4096 + pix;
                float cnew = fv * cst[cidx] + iv * gv;
                cst[cidx] = cnew;
                float e2c = __expf(2.f * cnew);
                float hv  = ov * (1.f - 2.f / (e2c + 1.f));
                out[((size_t)(t * 4 + img) * 64 + hc) * 4096 + pix] = hv;
                hbounce[((wv * N_ + n) * 16 + cl) * 16 + m * 4 + q] = f2bf(hv);
            }
        }
        __syncthreads();
        // coalesced hT write-out: [img][pix][ci] slice grp*16..grp*16+15
        if (tid < TH * 16) {
            int pixg = (py0 + (tid >> 4)) * 64 + px0 + (tid & 15);
            u32x4* dst = (u32x4*)(hout + ((size_t)img * 4096 + pixg) * 64 + grp * 16);
            u32x4* s0  = (u32x4*)(hbounce + tid * 16);
            dst[0] = s0[0];
            dst[1] = s0[1];
        }
    }
}

// ---------------------------------------------------------------------------
// BN finalize: reduce 1024 per-block partials per channel -> scale/shift
// ---------------------------------------------------------------------------
__global__ __launch_bounds__(256) void k_bn_fin(
    const float2* __restrict__ prt, const float* __restrict__ bx,
    const float* __restrict__ gamma, const float* __restrict__ beta,
    float* __restrict__ ss) {
    int c = blockIdx.x;                       // 256 blocks
    const float2* p = prt + (size_t)c * 1024;
    float s = 0.f, sq = 0.f;
    for (int i = threadIdx.x; i < 1024; i += 256) {
        float2 v = p[i]; s += v.x; sq += v.y;
    }
    __shared__ float rs[256], rq[256];
    int tid = threadIdx.x;
    rs[tid] = s; rq[tid] = sq;
    __syncthreads();
    for (int off = 128; off > 0; off >>= 1) {
        if (tid < off) { rs[tid] += rs[tid + off]; rq[tid] += rq[tid + off]; }
        __syncthreads();
    }
    if (tid == 0) {
        float mean = rs[0] * (1.f / 262144.f);
        float var  = rq[0] * (1.f / 262144.f) - mean * mean;
        float sc   = gamma[c] * rsqrtf(var + 1e-5f);
        ss[c]       = sc;
        // conv bias bx cancels exactly in train-mode BN (mean contains it);
        // y was stored WITHOUT bias, so stats already match the bias-free conv:
        ss[256 + c] = beta[c] - mean * sc;
        (void)bx;
    }
}

// ---------------------------------------------------------------------------
extern "C" void kernel_launch(void* const* d_in, const int* in_sizes, int n_in,
                              void* d_out, int out_size, void* d_ws, size_t ws_size,
                              hipStream_t stream) {
    const float* x     = (const float*)d_in[0];
    const float* Wx    = (const float*)d_in[1];
    const float* bx    = (const float*)d_in[2];
    const float* gamma = (const float*)d_in[3];
    const float* beta  = (const float*)d_in[4];
    const float* Wh    = (const float*)d_in[5];
    float* out = (float*)d_out;

    char* ws = (char*)d_ws;
    unsigned short* y   = (unsigned short*)ws;                  // 134,217,728
    unsigned short* Axp = (unsigned short*)(ws + 134217728);    //     294,912
    unsigned short* Ahp = (unsigned short*)(ws + 134512640);    //     294,912
    float*          ss  = (float*)(ws + 134807552);             //       2,048
    float*          cs  = (float*)(ws + 134809600);             //   4,194,304
    // prt and hA share a 2 MB slot: prt is produced by k_conv<0> and fully
    // consumed by k_bn_fin before step t=1 first writes hA (t=0 writes hB).
    float2*         prt = (float2*)(ws + 139003904);            //   2,097,152
    unsigned short* hA  = (unsigned short*)(ws + 139003904);    //   (alias)
    unsigned short* hB  = (unsigned short*)(ws + 141101056);    //   2,097,152
    // total 143,198,208 B

    // xT scratch lives in d_out (dead once steps start overwriting it)
    unsigned short* xT = (unsigned short*)d_out;

    k_xT  <<<1024, 256, 0, stream>>>(x, xT);
    k_pack<<< 576, 256, 0, stream>>>(Wx, Axp, 0);
    k_pack<<< 576, 256, 0, stream>>>(Wh, Ahp, 1);
    hipMemsetAsync(cs, 0, 4194304, stream);

    k_conv<0><<<4096, 256, 0, stream>>>(xT, Axp, y, nullptr, nullptr, nullptr,
                                        nullptr, prt, 0, 0);
    k_bn_fin<<<256, 256, 0, stream>>>(prt, bx, gamma, beta, ss);

    unsigned short* hbuf[2] = {hA, hB};
    for (int t = 0; t < 16; ++t) {
        k_conv<1><<<512, 256, 0, stream>>>(hbuf[t & 1], Ahp, y, ss, cs,
                                           hbuf[(t + 1) & 1], out, nullptr,
                                           t, t == 0 ? 1 : 0);
    }
}

// Round 7
// 480.678 us; speedup vs baseline: 1.2571x; 1.2571x over previous
//
#include <hip/hip_runtime.h>
#include <hip/hip_bf16.h>

// T=16, N=4, Cin=hidden=64, C4=256, H=W=64
typedef float        f32x4  __attribute__((ext_vector_type(4)));
typedef unsigned int u32x4  __attribute__((ext_vector_type(4)));
typedef __bf16       bf16x8 __attribute__((ext_vector_type(8)));

__device__ __forceinline__ unsigned short f2bf(float f) {
    unsigned u = __builtin_bit_cast(unsigned, f);
    u += 0x7fffu + ((u >> 16) & 1u);          // RTN-even (finite inputs)
    return (unsigned short)(u >> 16);
}
__device__ __forceinline__ float bf2f(unsigned short u) {
    union { unsigned ui; float f; } c; c.ui = ((unsigned)u) << 16; return c.f;
}

// ---------------------------------------------------------------------------
// xT: [img][pix][ci] bf16  <-  x [img][ci][pix] f32
// ---------------------------------------------------------------------------
__global__ __launch_bounds__(256) void k_xT(const float* __restrict__ x,
                                            unsigned short* __restrict__ xT) {
    int bid = blockIdx.x;                // 1024
    int img = bid >> 4;
    int p   = (bid & 15) * 256 + threadIdx.x;
    const float* xi = x + (size_t)img * 64 * 4096 + p;
    unsigned short r[64];
#pragma unroll
    for (int ci = 0; ci < 64; ++ci) r[ci] = f2bf(xi[(size_t)ci * 4096]);
    u32x4* dst = (u32x4*)(xT + ((size_t)img * 4096 + p) * 64);
#pragma unroll
    for (int c8 = 0; c8 < 8; ++c8) dst[c8] = *(u32x4*)&r[c8 * 8];
}

// ---------------------------------------------------------------------------
// Pack weights [256][64][3][3] f32 -> A bf16 [row][tap][kb][chunk] with the
// per-row chunk pre-swizzle (round-4 verified): stored slot s holds source
// chunk s^(row&3).  ks = tap*2+kb; byte offset of ks-slab within row = ks*64.
// gatePerm: row = hc*4+g  ->  orig co = g*64+hc   (for Wh)
// ---------------------------------------------------------------------------
__global__ __launch_bounds__(256) void k_pack(const float* __restrict__ W,
                                              unsigned short* __restrict__ Ap,
                                              int gatePerm) {
    int idx = blockIdx.x * 256 + threadIdx.x;      // 576 blocks
    if (idx >= 256 * 576) return;
    int row = idx / 576, k = idx % 576;
    int tap = k / 64, cil = k % 64;
    int kb = cil >> 5, w32 = cil & 31;
    int s = w32 >> 3, e = w32 & 7;
    int ci = kb * 32 + ((s ^ (row & 3)) << 3) + e;     // pre-swizzle chunks
    int co = gatePerm ? ((row & 3) * 64 + (row >> 2)) : row;
    Ap[idx] = f2bf(W[((size_t)co * 64 + ci) * 9 + tap]);
}

// ---------------------------------------------------------------------------
// Unified MFMA conv core (round-4 verified k-loop algebra).
// MODE0 (x2h): 128co x 256px (16x16 tile), m=8, grid 64img*16tile*2cog = 2048.
// MODE1 (step): 64co x 128px (8x16 tile),  m=4, grid 4img*32tile*4hcg = 512.
// A double-buffered in LDS (global->reg->LDS), halo 8-slot XOR swizzle.
// ---------------------------------------------------------------------------
template<int MODE>
__global__ __launch_bounds__(256) void k_conv(
    const unsigned short* __restrict__ src,   // [img][4096][64] bf16
    const unsigned short* __restrict__ Ap,    // packed weights [row][18][32]
    unsigned short* __restrict__ ybf,         // MODE0: out, MODE1: in
    const float* __restrict__ ss,             // [2][256] scale/shift (MODE1)
    float* __restrict__ cst,                  // [4][64][4096] (MODE1)
    unsigned short* __restrict__ hout,        // [4][4096][64] (MODE1)
    float* __restrict__ out,                  // [16][4][64][4096] (MODE1)
    float2* __restrict__ prt,                 // [256ch][1024] BN partials (MODE0)
    int t, int first)
{
    constexpr int MR    = MODE ? 4 : 8;       // m-frags per wave (rows = MR*16)
    constexpr int TH    = MODE ? 8 : 16;      // tile rows
    constexpr int N_    = MODE ? 2 : 4;       // pixel-row groups per wave
    constexpr int HR    = TH + 2;             // halo rows
    constexpr int RND   = MR / 4;             // A staging rounds (64 rows each)
    constexpr int SLAB  = MR * 16 * 64;       // A slab bytes (rows*64B)

    __shared__ __align__(16) unsigned short halo[HR * 18 * 64];
    __shared__ __align__(16) unsigned short As[2][MR * 512];

    const int bid  = blockIdx.x;
    const int grp  = MODE ? (bid & 3) : (bid & 1);
    const int tile = MODE ? ((bid >> 2) & 31) : ((bid >> 1) & 15);
    const int img  = MODE ? (bid >> 7) : (bid >> 5);
    const int py0 = (tile >> 2) * TH, px0 = (tile & 3) * 16;
    const int tid = threadIdx.x;
    const int wv = tid >> 6, lane = tid & 63;
    const int cl = lane & 15, q = lane >> 4;
    const int rowbase = grp * MR * 16;

    f32x4 acc[MR][N_];
#pragma unroll
    for (int m = 0; m < MR; ++m)
#pragma unroll
        for (int n = 0; n < N_; ++n)
            acc[m][n] = (f32x4){0.f, 0.f, 0.f, 0.f};

    const bool skip = (MODE == 1) && first;

    if (!skip) {
        // ---- halo staging: HRx18 positions x 8 ci-slots, XOR-swizzled ----
        const unsigned short* sb = src + (size_t)img * 4096 * 64;
        char* hB = (char*)halo;
        for (int tau = tid; tau < HR * 144; tau += 256) {
            int s = tau & 7, hcc = (tau >> 3) % 18, hrr = tau / 144;
            int gy = py0 + hrr - 1, gx = px0 + hcc - 1;
            u32x4 v = {0u, 0u, 0u, 0u};
            if ((unsigned)gy < 64u && (unsigned)gx < 64u)
                v = *(const u32x4*)(sb + ((gy * 64 + gx) * 64 + s * 8));
            *(u32x4*)(hB + (hrr * 18 + hcc) * 128 + ((s * 16) ^ ((hcc & 7) << 4))) = v;
        }
        // ---- A slab staging: MR*16 rows x 64B per ks (pre-swizzled src) ----
        const char* agp[RND];
        char*       awr[RND];
#pragma unroll
        for (int r2 = 0; r2 < RND; ++r2) {
            agp[r2] = (const char*)Ap +
                (size_t)(rowbase + r2 * 64 + (tid >> 2)) * 1152 + (tid & 3) * 16;
            awr[r2] = (char*)(&As[0][0]) + r2 * 4096 + (tid >> 2) * 64 + (tid & 3) * 16;
            *(u32x4*)awr[r2] = *(const u32x4*)agp[r2];          // ks = 0
        }
        __syncthreads();

        int aoff[MR];
#pragma unroll
        for (int m = 0; m < MR; ++m)
            aoff[m] = (m * 16 + cl) * 64 + ((q * 16) ^ ((cl & 3) << 4));

        const char* AsRd = (const char*)(&As[0][0]);
        int buf = 0;
        for (int ks = 0; ks < 18; ++ks) {
            bool have = ks < 17;
            u32x4 an[RND];
            if (have) {
#pragma unroll
                for (int r2 = 0; r2 < RND; ++r2)
                    an[r2] = *(const u32x4*)(agp[r2] + (ks + 1) * 64);
            }
            int tap = ks >> 1, kb = ks & 1;
            int ky = tap / 3, kx = tap - ky * 3;

            u32x4 af[MR];
#pragma unroll
            for (int m = 0; m < MR; ++m)
                af[m] = *(const u32x4*)(AsRd + buf * SLAB + aoff[m]);

            int hcv  = cl + kx;
            int cbase = hcv * 128 + ((kb * 64 + q * 16) ^ ((hcv & 7) << 4));
#pragma unroll
            for (int n = 0; n < N_; ++n) {
                int hr = wv * N_ + n + ky;
                u32x4 bv = *(const u32x4*)(hB + hr * 2304 + cbase);
                bf16x8 bfr = __builtin_bit_cast(bf16x8, bv);
#pragma unroll
                for (int m = 0; m < MR; ++m)
                    acc[m][n] = __builtin_amdgcn_mfma_f32_16x16x32_bf16(
                        __builtin_bit_cast(bf16x8, af[m]), bfr, acc[m][n], 0, 0, 0);
            }
            if (have) {
#pragma unroll
                for (int r2 = 0; r2 < RND; ++r2)
                    *(u32x4*)(awr[r2] + ((buf ^ 1) ? SLAB : 0)) = an[r2];
            }
            __syncthreads();
            buf ^= 1;
        }
    }

    if (MODE == 0) {
        // ---- y = conv (bias cancels in train-mode BN; never added) ----
#pragma unroll
        for (int m = 0; m < MR; ++m) {
            int co = rowbase + m * 16 + q * 4;
#pragma unroll
            for (int n = 0; n < N_; ++n) {
                int pix = (py0 + wv * N_ + n) * 64 + px0 + cl;
                unsigned short* yp = ybf + (size_t)img * 256 * 4096 + pix;
#pragma unroll
                for (int j = 0; j < 4; ++j)
                    yp[(size_t)(co + j) * 4096] = f2bf(acc[m][n][j]);
            }
        }
        // ---- fused BN partial stats: per-block 128-ch (sum, sumsq) ----
        __syncthreads();                     // halo/As reads all done
        float* bnred = (float*)halo;         // 128ch x 4wv x 2 = 4 KB reuse
#pragma unroll
        for (int m = 0; m < MR; ++m) {
#pragma unroll
            for (int j = 0; j < 4; ++j) {
                float s = 0.f, qq = 0.f;
#pragma unroll
                for (int n = 0; n < N_; ++n) {
                    float v = acc[m][n][j];
                    s += v; qq += v * v;
                }
#pragma unroll
                for (int mask = 1; mask <= 8; mask <<= 1) {
                    s  += __shfl_xor(s,  mask, 64);
                    qq += __shfl_xor(qq, mask, 64);
                }
                if (cl == 0) {
                    int ch = m * 16 + q * 4 + j;          // 0..127
                    bnred[ch * 8 + wv * 2]     = s;
                    bnred[ch * 8 + wv * 2 + 1] = qq;
                }
            }
        }
        __syncthreads();
        if (tid < 128) {
            float s = 0.f, qq = 0.f;
#pragma unroll
            for (int w = 0; w < 4; ++w) {
                s  += bnred[tid * 8 + w * 2];
                qq += bnred[tid * 8 + w * 2 + 1];
            }
            prt[(size_t)(rowbase + tid) * 1024 + img * 16 + tile] = make_float2(s, qq);
        }
    } else {
        unsigned short* hbounce = halo;          // 4 KB reuse
        __syncthreads();                         // halo reads done (all waves)
#pragma unroll
        for (int m = 0; m < MR; ++m) {
            int hc = grp * 16 + m * 4 + q;
            float sc[4], sh[4];
#pragma unroll
            for (int j = 0; j < 4; ++j) {
                sc[j] = ss[j * 64 + hc];
                sh[j] = ss[256 + j * 64 + hc];
            }
#pragma unroll
            for (int n = 0; n < N_; ++n) {
                int pix = (py0 + wv * N_ + n) * 64 + px0 + cl;
                float tmp[4];
#pragma unroll
                for (int j = 0; j < 4; ++j) {
                    float yv = bf2f(ybf[((size_t)((t * 4 + img) * 256 + j * 64 + hc)) * 4096 + pix]);
                    tmp[j] = acc[m][n][j] + sc[j] * yv + sh[j];
                }
                float iv = 1.f / (1.f + __expf(-tmp[0]));
                float fv = 1.f / (1.f + __expf(-tmp[1]));
                float ov = 1.f / (1.f + __expf(-tmp[2]));
                float e2 = __expf(2.f * tmp[3]);
                float gv = 1.f - 2.f / (e2 + 1.f);
                size_t cidx = ((size_t)img * 64 + hc) * 4096 + pix;
                float cnew = fv * cst[cidx] + iv * gv;
                cst[cidx] = cnew;
                float e2c = __expf(2.f * cnew);
                float hv  = ov * (1.f - 2.f / (e2c + 1.f));
                out[((size_t)(t * 4 + img) * 64 + hc) * 4096 + pix] = hv;
                hbounce[((wv * N_ + n) * 16 + cl) * 16 + m * 4 + q] = f2bf(hv);
            }
        }
        __syncthreads();
        // coalesced hT write-out: [img][pix][ci] slice grp*16..grp*16+15
        if (tid < TH * 16) {
            int pixg = (py0 + (tid >> 4)) * 64 + px0 + (tid & 15);
            u32x4* dst = (u32x4*)(hout + ((size_t)img * 4096 + pixg) * 64 + grp * 16);
            u32x4* s0  = (u32x4*)(hbounce + tid * 16);
            dst[0] = s0[0];
            dst[1] = s0[1];
        }
    }
}

// ---------------------------------------------------------------------------
// BN finalize: reduce 1024 per-block partials per channel -> scale/shift
// ---------------------------------------------------------------------------
__global__ __launch_bounds__(256) void k_bn_fin(
    const float2* __restrict__ prt, const float* __restrict__ bx,
    const float* __restrict__ gamma, const float* __restrict__ beta,
    float* __restrict__ ss) {
    int c = blockIdx.x;                       // 256 blocks
    const float2* p = prt + (size_t)c * 1024;
    float s = 0.f, sq = 0.f;
    for (int i = threadIdx.x; i < 1024; i += 256) {
        float2 v = p[i]; s += v.x; sq += v.y;
    }
    __shared__ float rs[256], rq[256];
    int tid = threadIdx.x;
    rs[tid] = s; rq[tid] = sq;
    __syncthreads();
    for (int off = 128; off > 0; off >>= 1) {
        if (tid < off) { rs[tid] += rs[tid + off]; rq[tid] += rq[tid + off]; }
        __syncthreads();
    }
    if (tid == 0) {
        float mean = rs[0] * (1.f / 262144.f);
        float var  = rq[0] * (1.f / 262144.f) - mean * mean;
        float sc   = gamma[c] * rsqrtf(var + 1e-5f);
        ss[c]       = sc;
        // conv bias bx cancels exactly in train-mode BN (mean contains it);
        // y was stored WITHOUT bias, so stats already match the bias-free conv:
        ss[256 + c] = beta[c] - mean * sc;
        (void)bx;
    }
}

// ---------------------------------------------------------------------------
extern "C" void kernel_launch(void* const* d_in, const int* in_sizes, int n_in,
                              void* d_out, int out_size, void* d_ws, size_t ws_size,
                              hipStream_t stream) {
    const float* x     = (const float*)d_in[0];
    const float* Wx    = (const float*)d_in[1];
    const float* bx    = (const float*)d_in[2];
    const float* gamma = (const float*)d_in[3];
    const float* beta  = (const float*)d_in[4];
    const float* Wh    = (const float*)d_in[5];
    float* out = (float*)d_out;

    char* ws = (char*)d_ws;
    unsigned short* y   = (unsigned short*)ws;                  // 134,217,728
    unsigned short* Axp = (unsigned short*)(ws + 134217728);    //     294,912
    unsigned short* Ahp = (unsigned short*)(ws + 134512640);    //     294,912
    float*          ss  = (float*)(ws + 134807552);             //       2,048
    float*          cs  = (float*)(ws + 134809600);             //   4,194,304
    // prt and hA share a 2 MB slot: prt is produced by k_conv<0> and fully
    // consumed by k_bn_fin before step t=1 first writes hA (t=0 writes hB).
    float2*         prt = (float2*)(ws + 139003904);            //   2,097,152
    unsigned short* hA  = (unsigned short*)(ws + 139003904);    //   (alias)
    unsigned short* hB  = (unsigned short*)(ws + 141101056);    //   2,097,152
    // total 143,198,208 B

    // xT scratch lives in d_out (dead once steps start overwriting it)
    unsigned short* xT = (unsigned short*)d_out;

    k_xT  <<<1024, 256, 0, stream>>>(x, xT);
    k_pack<<< 576, 256, 0, stream>>>(Wx, Axp, 0);
    k_pack<<< 576, 256, 0, stream>>>(Wh, Ahp, 1);
    hipMemsetAsync(cs, 0, 4194304, stream);

    k_conv<0><<<2048, 256, 0, stream>>>(xT, Axp, y, nullptr, nullptr, nullptr,
                                        nullptr, prt, 0, 0);
    k_bn_fin<<<256, 256, 0, stream>>>(prt, bx, gamma, beta, ss);

    unsigned short* hbuf[2] = {hA, hB};
    for (int t = 0; t < 16; ++t) {
        k_conv<1><<<512, 256, 0, stream>>>(hbuf[t & 1], Ahp, y, ss, cs,
                                           hbuf[(t + 1) & 1], out, nullptr,
                                           t, t == 0 ? 1 : 0);
    }
}

// Round 8
// 389.076 us; speedup vs baseline: 1.5530x; 1.2354x over previous
//
#include <hip/hip_runtime.h>
#include <hip/hip_bf16.h>

// T=16, N=4, Cin=hidden=64, C4=256, H=W=64
typedef float        f32x4  __attribute__((ext_vector_type(4)));
typedef unsigned int u32x4  __attribute__((ext_vector_type(4)));
typedef __bf16       bf16x8 __attribute__((ext_vector_type(8)));

__device__ __forceinline__ unsigned short f2bf(float f) {
    unsigned u = __builtin_bit_cast(unsigned, f);
    u += 0x7fffu + ((u >> 16) & 1u);          // RTN-even (finite inputs)
    return (unsigned short)(u >> 16);
}
__device__ __forceinline__ float bf2f(unsigned short u) {
    union { unsigned ui; float f; } c; c.ui = ((unsigned)u) << 16; return c.f;
}

// ---------------------------------------------------------------------------
// xT: [img][pix][ci] bf16  <-  x [img][ci][pix] f32
// ---------------------------------------------------------------------------
__global__ __launch_bounds__(256) void k_xT(const float* __restrict__ x,
                                            unsigned short* __restrict__ xT) {
    int bid = blockIdx.x;                // 1024
    int img = bid >> 4;
    int p   = (bid & 15) * 256 + threadIdx.x;
    const float* xi = x + (size_t)img * 64 * 4096 + p;
    unsigned short r[64];
#pragma unroll
    for (int ci = 0; ci < 64; ++ci) r[ci] = f2bf(xi[(size_t)ci * 4096]);
    u32x4* dst = (u32x4*)(xT + ((size_t)img * 4096 + p) * 64);
#pragma unroll
    for (int c8 = 0; c8 < 8; ++c8) dst[c8] = *(u32x4*)&r[c8 * 8];
}

// ---------------------------------------------------------------------------
// Pack weights [256][64][3][3] f32 -> A bf16 [row][ks][4 chunk-slots of 16B],
// chunk pre-swizzle (r4-verified): stored slot s holds source chunk s^(row&3).
// ks = tap*2 + kb.  row = hc*4 + g  <->  orig co = g*64 + hc (both Wx and Wh;
// y is stored gate-interleaved so x2h must use the same row permutation).
// ---------------------------------------------------------------------------
__global__ __launch_bounds__(256) void k_pack(const float* __restrict__ W,
                                              unsigned short* __restrict__ Ap) {
    int idx = blockIdx.x * 256 + threadIdx.x;      // 576 blocks
    if (idx >= 256 * 576) return;
    int row = idx / 576, k = idx % 576;
    int ks = k / 32, w32 = k % 32;
    int tap = ks >> 1, kb = ks & 1;
    int s = w32 >> 3, e = w32 & 7;
    int ci = kb * 32 + ((s ^ (row & 3)) << 3) + e;     // pre-swizzle chunks
    int co = (row & 3) * 64 + (row >> 2);              // gate permutation
    Ap[idx] = f2bf(W[((size_t)co * 64 + ci) * 9 + tap]);
}

// ---------------------------------------------------------------------------
// Unified MFMA conv core, phase-staged A (barrier-free 9-tap inner loops).
// MODE0 (x2h): 64co x 256px (16x16 tile), grid 64img*16tile*4cog = 4096.
// MODE1 (step): 64co x 128px (8x16 tile), grid 4img*32tile*4hcg  =  512.
// y layout: [img][pix][256 r] bf16, r = hc*4+g (gate-interleaved).
// ---------------------------------------------------------------------------
template<int MODE>
__global__ __launch_bounds__(256) void k_conv(
    const unsigned short* __restrict__ src,   // [img][4096][64] bf16
    const unsigned short* __restrict__ Ap,    // packed weights [row][18][64B]
    unsigned short* __restrict__ ybf,         // MODE0: out, MODE1: in
    const float* __restrict__ ss,             // [2][256] scale/shift (MODE1)
    float* __restrict__ cst,                  // [4][64][4096] (MODE1)
    unsigned short* __restrict__ hout,        // [4][4096][64] (MODE1)
    float* __restrict__ out,                  // [16][4][64][4096] (MODE1)
    float2* __restrict__ prt,                 // [256ch][1024] BN partials (MODE0)
    int t, int first)
{
    constexpr int TH = MODE ? 8 : 16;         // tile rows
    constexpr int N_ = MODE ? 2 : 4;          // pixel-row groups per wave
    constexpr int HR = TH + 2;                // halo rows

    __shared__ __align__(16) unsigned short halo[HR * 18 * 64]; // 41472/23040 B
    __shared__ __align__(16) unsigned short AsH[9 * 2048];      // 36864 B

    const int bid  = blockIdx.x;
    const int grp  = bid & 3;
    const int tile = MODE ? ((bid >> 2) & 31) : ((bid >> 2) & 15);
    const int img  = MODE ? (bid >> 7) : (bid >> 6);
    const int py0 = (tile >> 2) * TH, px0 = (tile & 3) * 16;
    const int tid = threadIdx.x;
    const int wv = tid >> 6, lane = tid & 63;
    const int cl = lane & 15, q = lane >> 4;
    const int rowbase = grp * 64;

    f32x4 acc[4][N_];
#pragma unroll
    for (int m = 0; m < 4; ++m)
#pragma unroll
        for (int n = 0; n < N_; ++n)
            acc[m][n] = (f32x4){0.f, 0.f, 0.f, 0.f};

    const bool skip = (MODE == 1) && first;

    if (!skip) {
        // ---- A: prefetch kb=1 slabs to regs, stage kb=0 slabs to LDS ----
        const int srow = tid >> 2, sslot = tid & 3;
        const char* agp = (const char*)Ap + (size_t)(rowbase + srow) * 1152 + sslot * 16;
        char* awr = (char*)AsH + srow * 64 + sslot * 16;
        u32x4 a1[9];
#pragma unroll
        for (int tp = 0; tp < 9; ++tp)
            a1[tp] = *(const u32x4*)(agp + (tp * 2 + 1) * 64);
#pragma unroll
        for (int tp = 0; tp < 9; ++tp)
            *(u32x4*)(awr + tp * 4096) = *(const u32x4*)(agp + (tp * 2) * 64);

        // ---- halo staging: HRx18 positions x 8 ci-slots, XOR-swizzled ----
        const unsigned short* sb = src + (size_t)img * 4096 * 64;
        char* hB = (char*)halo;
        for (int tau = tid; tau < HR * 144; tau += 256) {
            int s = tau & 7, hcc = (tau >> 3) % 18, hrr = tau / 144;
            int gy = py0 + hrr - 1, gx = px0 + hcc - 1;
            u32x4 v = {0u, 0u, 0u, 0u};
            if ((unsigned)gy < 64u && (unsigned)gx < 64u)
                v = *(const u32x4*)(sb + ((gy * 64 + gx) * 64 + s * 8));
            *(u32x4*)(hB + (hrr * 18 + hcc) * 128 + ((s * 16) ^ ((hcc & 7) << 4))) = v;
        }
        __syncthreads();

        int aoff[4];
#pragma unroll
        for (int m = 0; m < 4; ++m)
            aoff[m] = (m * 16 + cl) * 64 + ((q * 16) ^ ((cl & 3) << 4));

        auto computeHalf = [&](int kb) {
#pragma unroll
            for (int tap = 0; tap < 9; ++tap) {
                int ky = tap / 3, kx = tap - ky * 3;
                u32x4 af[4];
#pragma unroll
                for (int m = 0; m < 4; ++m)
                    af[m] = *(const u32x4*)((const char*)AsH + tap * 4096 + aoff[m]);
                int hcv  = cl + kx;
                int cbase = hcv * 128 + ((kb * 64 + q * 16) ^ ((hcv & 7) << 4));
#pragma unroll
                for (int n = 0; n < N_; ++n) {
                    int hr = wv * N_ + n + ky;
                    u32x4 bv = *(const u32x4*)(hB + hr * 2304 + cbase);
                    bf16x8 bfr = __builtin_bit_cast(bf16x8, bv);
#pragma unroll
                    for (int m = 0; m < 4; ++m)
                        acc[m][n] = __builtin_amdgcn_mfma_f32_16x16x32_bf16(
                            __builtin_bit_cast(bf16x8, af[m]), bfr, acc[m][n], 0, 0, 0);
                }
            }
        };

        computeHalf(0);                 // barrier-free 9 taps
        __syncthreads();                // everyone done reading A(kb=0)
#pragma unroll
        for (int tp = 0; tp < 9; ++tp)
            *(u32x4*)(awr + tp * 4096) = a1[tp];
        __syncthreads();
        computeHalf(1);                 // barrier-free 9 taps
    }

    if (MODE == 0) {
        // ---- y[img][pix][r]: 8B packed store per (m,n) ----
#pragma unroll
        for (int m = 0; m < 4; ++m) {
#pragma unroll
            for (int n = 0; n < N_; ++n) {
                int pix = (py0 + wv * N_ + n) * 64 + px0 + cl;
                uint2 w;
                w.x = (unsigned)f2bf(acc[m][n][0]) | ((unsigned)f2bf(acc[m][n][1]) << 16);
                w.y = (unsigned)f2bf(acc[m][n][2]) | ((unsigned)f2bf(acc[m][n][3]) << 16);
                *(uint2*)(ybf + ((size_t)img * 4096 + pix) * 256 + rowbase + m * 16 + q * 4) = w;
            }
        }
        // ---- fused BN partial stats: per-block 64-channel (sum, sumsq) ----
        __syncthreads();                     // halo/AsH reads all done
        float* bnred = (float*)halo;         // 512 B reuse
#pragma unroll
        for (int m = 0; m < 4; ++m) {
#pragma unroll
            for (int j = 0; j < 4; ++j) {
                float s = 0.f, qq = 0.f;
#pragma unroll
                for (int n = 0; n < N_; ++n) {
                    float v = acc[m][n][j];
                    s += v; qq += v * v;
                }
#pragma unroll
                for (int mask = 1; mask <= 8; mask <<= 1) {
                    s  += __shfl_xor(s,  mask, 64);
                    qq += __shfl_xor(qq, mask, 64);
                }
                if (cl == 0) {
                    int ci_ = (wv * 4 + q) * 16 + m * 4 + j;
                    bnred[ci_ * 2]     = s;
                    bnred[ci_ * 2 + 1] = qq;
                }
            }
        }
        __syncthreads();
        if (tid < 64) {
            int m_ = tid >> 4, qj = tid & 15;      // local ch = m*16 + q*4 + j
            float s = 0.f, qq = 0.f;
#pragma unroll
            for (int w = 0; w < 4; ++w) {
                int idx = ((w * 4 + (qj >> 2)) * 16 + m_ * 4 + (qj & 3)) * 2;
                s += bnred[idx]; qq += bnred[idx + 1];
            }
            prt[(size_t)(rowbase + tid) * 1024 + img * 16 + tile] = make_float2(s, qq);
        }
    } else {
        unsigned short* hbounce = halo;          // 4 KB reuse
        __syncthreads();                         // halo reads done (all waves)
        const f32x4* sc4 = (const f32x4*)ss;
        const f32x4* sh4 = (const f32x4*)(ss + 256);
#pragma unroll
        for (int m = 0; m < 4; ++m) {
            int hc = grp * 16 + m * 4 + q;
            f32x4 sc = sc4[hc], sh = sh4[hc];
#pragma unroll
            for (int n = 0; n < N_; ++n) {
                int pix = (py0 + wv * N_ + n) * 64 + px0 + cl;
                uint2 yv = *(const uint2*)(ybf +
                    ((size_t)(t * 4 + img) * 4096 + pix) * 256 + hc * 4);
                float tmp[4];
                tmp[0] = acc[m][n][0] + sc[0] * bf2f((unsigned short)(yv.x & 0xffffu)) + sh[0];
                tmp[1] = acc[m][n][1] + sc[1] * bf2f((unsigned short)(yv.x >> 16))     + sh[1];
                tmp[2] = acc[m][n][2] + sc[2] * bf2f((unsigned short)(yv.y & 0xffffu)) + sh[2];
                tmp[3] = acc[m][n][3] + sc[3] * bf2f((unsigned short)(yv.y >> 16))     + sh[3];
                float iv = 1.f / (1.f + __expf(-tmp[0]));
                float fv = 1.f / (1.f + __expf(-tmp[1]));
                float ov = 1.f / (1.f + __expf(-tmp[2]));
                float e2 = __expf(2.f * tmp[3]);
                float gv = 1.f - 2.f / (e2 + 1.f);
                size_t cidx = ((size_t)img * 64 + hc) * 4096 + pix;
                float cnew = fv * cst[cidx] + iv * gv;
                cst[cidx] = cnew;
                float e2c = __expf(2.f * cnew);
                float hv  = ov * (1.f - 2.f / (e2c + 1.f));
                out[((size_t)(t * 4 + img) * 64 + hc) * 4096 + pix] = hv;
                hbounce[((wv * N_ + n) * 16 + cl) * 16 + m * 4 + q] = f2bf(hv);
            }
        }
        __syncthreads();
        // coalesced hT write-out: [img][pix][ci] slice grp*16..grp*16+15
        if (tid < TH * 16) {
            int pixg = (py0 + (tid >> 4)) * 64 + px0 + (tid & 15);
            u32x4* dst = (u32x4*)(hout + ((size_t)img * 4096 + pixg) * 64 + grp * 16);
            u32x4* s0  = (u32x4*)(hbounce + tid * 16);
            dst[0] = s0[0];
            dst[1] = s0[1];
        }
    }
}

// ---------------------------------------------------------------------------
// BN finalize: reduce 1024 per-block partials per channel r -> scale/shift.
// r = hc*4+g  ->  orig co = (r&3)*64 + (r>>2) for gamma/beta lookup.
// ---------------------------------------------------------------------------
__global__ __launch_bounds__(256) void k_bn_fin(
    const float2* __restrict__ prt, const float* __restrict__ bx,
    const float* __restrict__ gamma, const float* __restrict__ beta,
    float* __restrict__ ss) {
    int c = blockIdx.x;                       // 256 blocks (r-index)
    const float2* p = prt + (size_t)c * 1024;
    float s = 0.f, sq = 0.f;
    for (int i = threadIdx.x; i < 1024; i += 256) {
        float2 v = p[i]; s += v.x; sq += v.y;
    }
    __shared__ float rs[256], rq[256];
    int tid = threadIdx.x;
    rs[tid] = s; rq[tid] = sq;
    __syncthreads();
    for (int off = 128; off > 0; off >>= 1) {
        if (tid < off) { rs[tid] += rs[tid + off]; rq[tid] += rq[tid + off]; }
        __syncthreads();
    }
    if (tid == 0) {
        int co = (c & 3) * 64 + (c >> 2);
        float mean = rs[0] * (1.f / 262144.f);
        float var  = rq[0] * (1.f / 262144.f) - mean * mean;
        float sc   = gamma[co] * rsqrtf(var + 1e-5f);
        ss[c]       = sc;
        // conv bias bx cancels exactly in train-mode BN (mean contains it);
        // y was stored WITHOUT bias, so stats already match the bias-free conv:
        ss[256 + c] = beta[co] - mean * sc;
        (void)bx;
    }
}

// ---------------------------------------------------------------------------
extern "C" void kernel_launch(void* const* d_in, const int* in_sizes, int n_in,
                              void* d_out, int out_size, void* d_ws, size_t ws_size,
                              hipStream_t stream) {
    const float* x     = (const float*)d_in[0];
    const float* Wx    = (const float*)d_in[1];
    const float* bx    = (const float*)d_in[2];
    const float* gamma = (const float*)d_in[3];
    const float* beta  = (const float*)d_in[4];
    const float* Wh    = (const float*)d_in[5];
    float* out = (float*)d_out;

    char* ws = (char*)d_ws;
    unsigned short* y   = (unsigned short*)ws;                  // 134,217,728
    unsigned short* Axp = (unsigned short*)(ws + 134217728);    //     294,912
    unsigned short* Ahp = (unsigned short*)(ws + 134512640);    //     294,912
    float*          ss  = (float*)(ws + 134807552);             //       2,048
    float*          cs  = (float*)(ws + 134809600);             //   4,194,304
    // prt and hA share a 2 MB slot: prt is produced by k_conv<0> and fully
    // consumed by k_bn_fin before step t=1 first writes hA (t=0 writes hB).
    float2*         prt = (float2*)(ws + 139003904);            //   2,097,152
    unsigned short* hA  = (unsigned short*)(ws + 139003904);    //   (alias)
    unsigned short* hB  = (unsigned short*)(ws + 141101056);    //   2,097,152
    // total 143,198,208 B

    // xT scratch lives in d_out (dead once steps start overwriting it)
    unsigned short* xT = (unsigned short*)d_out;

    k_xT  <<<1024, 256, 0, stream>>>(x, xT);
    k_pack<<< 576, 256, 0, stream>>>(Wx, Axp);
    k_pack<<< 576, 256, 0, stream>>>(Wh, Ahp);
    hipMemsetAsync(cs, 0, 4194304, stream);

    k_conv<0><<<4096, 256, 0, stream>>>(xT, Axp, y, nullptr, nullptr, nullptr,
                                        nullptr, prt, 0, 0);
    k_bn_fin<<<256, 256, 0, stream>>>(prt, bx, gamma, beta, ss);

    unsigned short* hbuf[2] = {hA, hB};
    for (int t = 0; t < 16; ++t) {
        k_conv<1><<<512, 256, 0, stream>>>(hbuf[t & 1], Ahp, y, ss, cs,
                                           hbuf[(t + 1) & 1], out, nullptr,
                                           t, t == 0 ? 1 : 0);
    }
}